// Round 1
// 80.325 us; speedup vs baseline: 1.0007x; 1.0007x over previous
//
#include <hip/hip_runtime.h>
#include <math.h>

#define HDIM 512
#define NH   32
#define LTOT 8192
#define HALF 4096   // l-range per block
#define CHUNK 16    // consecutive l per thread (8 packed pairs)
#define TPB  256

typedef float v2f __attribute__((ext_vector_type(2)));

// One block = one (h, l-half). Threads 0..31 compute per-(h,n) params into LDS.
// Each thread evaluates CHUNK consecutive l via an exact transcendental start
// plus a PACKED stride-2 real recurrence: with u_j = 2Re(Ceff w^j K(l0)),
// the pairs P_k = (u_{2k}, u_{2k+1}) satisfy P_{k+1} = a2*P_k - b2*P_{k-1}
// elementwise, a2 = 2Re(w^2), b2 = |w|^4 (roots w^2, conj -- |.|<1, stable).
//
// This version software-pipelines the per-pole LDS parameter reads: poles are
// processed in PAIRS, and the next pair's 6 float4 params are loaded one full
// iteration (~220 issue cycles) before use, hiding the ~120-cycle LDS latency
// that previously stalled every pole iteration (3 dependent ds_read_b128).
__global__ __launch_bounds__(TPB, 4) void s4_kernel(
    const float* __restrict__ log_dt,
    const float* __restrict__ log_A_real,
    const float* __restrict__ A_imag,
    const float* __restrict__ Bmat,
    const float* __restrict__ Cmat,
    float* __restrict__ out)
{
    __shared__ float4 p0[NH]; // re*log2e, im/(2pi), a2=2Re(w^2), b2=|w|^4
    __shared__ float4 p1[NH]; // E0r, E1r, E0i, E1i   (Ej = 2*Ceff*w^j)
    __shared__ float4 p2[NH]; // E2r, E3r, E2i, E3i

    const int bid  = blockIdx.x;
    const int h    = bid >> 1;
    const int half = bid & 1;
    const int tid  = threadIdx.x;

    if (tid < NH) {
        const int n   = tid;
        const int idx = h * NH + n;
        const float dt = expf(log_dt[h]);
        const float Ar = -expf(log_A_real[idx]);   // A = -exp(lar) - i*A_imag
        const float Ai = -A_imag[idx];
        const float re = Ar * dt;                  // dtA (re < 0)
        const float im = Ai * dt;
        float sw, cw;
        sincosf(im, &sw, &cw);                     // precise: small arg
        const float er = expf(re);
        const float wr = er * cw;                  // w = exp(dtA)
        const float wi = er * sw;
        // (w - 1) / A
        const float inv = 1.0f / (Ar * Ar + Ai * Ai);
        const float nr = wr - 1.0f, ni = wi;
        const float qr = (nr * Ar + ni * Ai) * inv;
        const float qi = (ni * Ar - nr * Ai) * inv;
        // E0 = 2 * Bc * Cc * (w-1)/A
        const float Br = Bmat[2 * idx], Bi = Bmat[2 * idx + 1];
        const float Cr = Cmat[2 * idx], Ci = Cmat[2 * idx + 1];
        const float bcr = Br * Cr - Bi * Ci;
        const float bci = Br * Ci + Bi * Cr;
        const float e0r = 2.0f * (bcr * qr - bci * qi);
        const float e0i = 2.0f * (bcr * qi + bci * qr);
        // Ej = E0 * w^j
        const float e1r = e0r * wr - e0i * wi, e1i = e0r * wi + e0i * wr;
        const float e2r = e1r * wr - e1i * wi, e2i = e1r * wi + e1i * wr;
        const float e3r = e2r * wr - e2i * wi, e3i = e2r * wi + e2i * wr;
        const float b1 = er * er;                  // |w|^2
        p0[n] = make_float4(re * 1.44269504089f, im * 0.15915494309f,
                            2.0f * (wr * wr - wi * wi), b1 * b1);
        p1[n] = make_float4(e0r, e1r, e0i, e1i);
        p2[n] = make_float4(e2r, e3r, e2i, e3i);
    }
    __syncthreads();

    const int   l0  = half * HALF + tid * CHUNK;
    const float l0f = (float)l0;

    v2f acc2[CHUNK / 2];
#pragma unroll
    for (int k = 0; k < CHUNK / 2; ++k) acc2[k] = v2f{0.0f, 0.0f};

    // Prefetch pair 0's params.
    float4 nP0a = p0[0], nP0b = p0[1];
    float4 nQ1a = p1[0], nQ2a = p2[0];
    float4 nQ1b = p1[1], nQ2b = p2[1];

#pragma unroll 1
    for (int n = 0; n < NH; n += 2) {
        const float4 P0a = nP0a, P0b = nP0b;
        const float4 Q1a = nQ1a, Q2a = nQ2a;
        const float4 Q1b = nQ1b, Q2b = nQ2b;
        // Issue next pair's loads NOW; results consumed next iteration,
        // so ds_read latency hides under this pair's arithmetic.
        if (n + 2 < NH) {
            nP0a = p0[n + 2]; nP0b = p0[n + 3];
            nQ1a = p1[n + 2]; nQ2a = p2[n + 2];
            nQ1b = p1[n + 3]; nQ2b = p2[n + 3];
        }

        // ---- pole n ----
        {
            const float ax2 = P0a.x * l0f;          // re*log2e*l0  (<= 0)
            if (ax2 >= -43.3f) {                    // else 2^-43.3 ~ 1e-13
                float ph = P0a.y * l0f;             // phase in revolutions
                ph = __builtin_amdgcn_fractf(ph);
                const float s = __builtin_amdgcn_sinf(ph);   // sin(2*pi*ph)
                const float c = __builtin_amdgcn_cosf(ph);
                const float e = __builtin_amdgcn_exp2f(ax2); // e^{re*l0}
                const float kr = e * c;             // K(l0) = exp(dtA*l0)
                const float ki = e * s;
                v2f Pa = v2f{Q1a.x, Q1a.y} * kr - v2f{Q1a.z, Q1a.w} * ki;
                v2f Pb = v2f{Q2a.x, Q2a.y} * kr - v2f{Q2a.z, Q2a.w} * ki;
                acc2[0] += Pa;
                acc2[1] += Pb;
                const v2f a2 = v2f{P0a.z, P0a.z};
                const v2f b2 = v2f{P0a.w, P0a.w};
#pragma unroll
                for (int k = 2; k < CHUNK / 2; ++k) {
                    const v2f Pn = a2 * Pb - b2 * Pa;  // pk_mul + pk_fma
                    acc2[k] += Pn;
                    Pa = Pb;
                    Pb = Pn;
                }
            }
        }
        // ---- pole n+1 ----
        {
            const float ax2 = P0b.x * l0f;
            if (ax2 >= -43.3f) {
                float ph = P0b.y * l0f;
                ph = __builtin_amdgcn_fractf(ph);
                const float s = __builtin_amdgcn_sinf(ph);
                const float c = __builtin_amdgcn_cosf(ph);
                const float e = __builtin_amdgcn_exp2f(ax2);
                const float kr = e * c;
                const float ki = e * s;
                v2f Pa = v2f{Q1b.x, Q1b.y} * kr - v2f{Q1b.z, Q1b.w} * ki;
                v2f Pb = v2f{Q2b.x, Q2b.y} * kr - v2f{Q2b.z, Q2b.w} * ki;
                acc2[0] += Pa;
                acc2[1] += Pb;
                const v2f a2 = v2f{P0b.z, P0b.z};
                const v2f b2 = v2f{P0b.w, P0b.w};
#pragma unroll
                for (int k = 2; k < CHUNK / 2; ++k) {
                    const v2f Pn = a2 * Pb - b2 * Pa;
                    acc2[k] += Pn;
                    Pa = Pb;
                    Pb = Pn;
                }
            }
        }
    }

    float4* o = (float4*)(out + (size_t)h * LTOT + l0);
#pragma unroll
    for (int j = 0; j < CHUNK / 4; ++j)
        o[j] = make_float4(acc2[2 * j].x, acc2[2 * j].y,
                           acc2[2 * j + 1].x, acc2[2 * j + 1].y);
}

extern "C" void kernel_launch(void* const* d_in, const int* in_sizes, int n_in,
                              void* d_out, int out_size, void* d_ws, size_t ws_size,
                              hipStream_t stream)
{
    (void)in_sizes; (void)n_in; (void)d_ws; (void)ws_size; (void)out_size;
    const float* log_dt     = (const float*)d_in[0];
    const float* log_A_real = (const float*)d_in[1];
    const float* A_imag     = (const float*)d_in[2];
    const float* Bmat       = (const float*)d_in[3];
    const float* Cmat       = (const float*)d_in[4];
    float* out = (float*)d_out;

    s4_kernel<<<dim3(HDIM * (LTOT / HALF)), dim3(TPB), 0, stream>>>(
        log_dt, log_A_real, A_imag, Bmat, Cmat, out);
}